// Round 15
// baseline (438.952 us; speedup 1.0000x reference)
//
#include <hip/hip_runtime.h>
#include <hip/hip_bf16.h>
#include <math.h>

#define DIMC 256
#define NB   4
#define HH   128
#define WW   128
#define HWs  16384
#define HID  256
#define C2   512
#define EPSf 1e-5f

typedef __hip_bfloat16 bf;
typedef unsigned short u16;
typedef unsigned int   u32;
typedef float f32x4  __attribute__((ext_vector_type(4)));
typedef u32   u32x4  __attribute__((ext_vector_type(4)));
typedef short bf16x8 __attribute__((ext_vector_type(8)));

__device__ __forceinline__ float b2f(bf v){ return __bfloat162float(v); }
__device__ __forceinline__ bf    f2b(float v){ return __float2bfloat16(v); }
__device__ __forceinline__ float ldf(const float* p){ return *p; }
__device__ __forceinline__ float ldf(const bf* p){ return __bfloat162float(*p); }
__device__ __forceinline__ void  sto(float* p, float v){ *p = v; }
__device__ __forceinline__ void  sto(bf* p, float v){ *p = f2b(v); }
__device__ __forceinline__ void unpack2(u32 u, float& a, float& b){
  union{u32 x; float f;} lo, hi;
  lo.x = u << 16; hi.x = u & 0xffff0000u;
  a = lo.f; b = hi.f;
}
__device__ __forceinline__ u32 pack2(float a, float b){
  bf h0 = f2b(a), h1 = f2b(b);
  return (u32)*(u16*)&h0 | ((u32)*(u16*)&h1 << 16);
}
__device__ __forceinline__ void unp4(uint2 u, float* d){
  unpack2(u.x, d[0], d[1]); unpack2(u.y, d[2], d[3]);
}

__device__ __forceinline__ float gelu_exact(float v){
  return 0.5f*v*(1.0f + erff(v*0.70710678118654752f));
}

// ---------------- merged weight fp32 -> bf16 convert (one launch) ----------------
__global__ __launch_bounds__(256) void cvt_all_kernel(
    const float* __restrict__ s0, const float* __restrict__ s1,
    const float* __restrict__ s2, const float* __restrict__ s3,
    u16* __restrict__ d0, u16* __restrict__ d1,
    u16* __restrict__ d2, u16* __restrict__ d3,
    int n0, int n1, int n2, int n3){
  int i = blockIdx.x*256 + threadIdx.x;
  if (i < n0){ bf h = f2b(s0[i]); d0[i] = *(u16*)&h; return; }
  i -= n0;
  if (i < n1){ bf h = f2b(s1[i]); d1[i] = *(u16*)&h; return; }
  i -= n1;
  if (i < n2){ bf h = f2b(s2[i]); d2[i] = *(u16*)&h; return; }
  i -= n2;
  if (i < n3){ bf h = f2b(s3[i]); d3[i] = *(u16*)&h; }
}

// ---------------- LayerNorm, fp32 in, 2 pixels/thread ----------------
__global__ __launch_bounds__(256) void ln1_2px_kernel(const float* __restrict__ x,
    const float* __restrict__ w, const float* __restrict__ bb, bf* __restrict__ y){
  int p2 = blockIdx.x*256 + threadIdx.x;   // pair id
  int b  = p2 >> 13;
  int sp = (p2 & 8191) << 1;
  const float* xb = x + (size_t)b*DIMC*HWs + sp;
  float s0=0.f, s1=0.f, q0=0.f, q1=0.f;
  for(int c=0;c<DIMC;c++){
    float2 v = *(const float2*)(xb + (size_t)c*HWs);
    s0 += v.x; q0 += v.x*v.x;
    s1 += v.y; q1 += v.y*v.y;
  }
  float mu0 = s0*(1.0f/DIMC), mu1 = s1*(1.0f/DIMC);
  float r0 = rsqrtf(q0*(1.0f/DIMC) - mu0*mu0 + EPSf);
  float r1 = rsqrtf(q1*(1.0f/DIMC) - mu1*mu1 + EPSf);
  u16* yb = (u16*)y + (size_t)b*DIMC*HWs + sp;
  for(int c=0;c<DIMC;c++){
    float2 v = *(const float2*)(xb + (size_t)c*HWs);
    float wc = w[c], bc = bb[c];
    *(u32*)(yb + (size_t)c*HWs) = pack2((v.x-mu0)*r0*wc + bc, (v.y-mu1)*r1*wc + bc);
  }
}

// ---------------- LayerNorm, bf16 in, 2 pixels/thread (packed u32 I/O) ----------------
__global__ __launch_bounds__(256) void ln2px_kernel(const bf* __restrict__ x,
    const float* __restrict__ w, const float* __restrict__ bb, bf* __restrict__ y){
  int p2 = blockIdx.x*256 + threadIdx.x;
  int b  = p2 >> 13;
  int sp = (p2 & 8191) << 1;
  const u16* xb = (const u16*)x + (size_t)b*DIMC*HWs + sp;
  float s0=0.f, s1=0.f, q0=0.f, q1=0.f;
  for(int c=0;c<DIMC;c++){
    u32 u = *(const u32*)(xb + (size_t)c*HWs);
    float a0, a1; unpack2(u, a0, a1);
    s0 += a0; q0 += a0*a0;
    s1 += a1; q1 += a1*a1;
  }
  float mu0 = s0*(1.0f/DIMC), mu1 = s1*(1.0f/DIMC);
  float r0 = rsqrtf(q0*(1.0f/DIMC) - mu0*mu0 + EPSf);
  float r1 = rsqrtf(q1*(1.0f/DIMC) - mu1*mu1 + EPSf);
  u16* yb = (u16*)y + (size_t)b*DIMC*HWs + sp;
  for(int c=0;c<DIMC;c++){
    u32 u = *(const u32*)(xb + (size_t)c*HWs);
    float a0, a1; unpack2(u, a0, a1);
    float wc = w[c], bc = bb[c];
    *(u32*)(yb + (size_t)c*HWs) = pack2((a0-mu0)*r0*wc + bc, (a1-mu1)*r1*wc + bc);
  }
}

// ---------------- global average pool per (b,c), vectorized ----------------
__global__ __launch_bounds__(256) void gp_kernel(const bf* __restrict__ y, float* __restrict__ gp){
  int bc = blockIdx.x;
  const u32x4* pl = (const u32x4*)(y + (size_t)bc*HWs);
  float s = 0.f;
  for(int i=threadIdx.x;i<2048;i+=256){
    u32x4 v = pl[i];
    #pragma unroll
    for(int q=0;q<4;q++){
      float a0, a1; unpack2(((const u32*)&v)[q], a0, a1);
      s += a0 + a1;
    }
  }
  __shared__ float red[256];
  red[threadIdx.x] = s; __syncthreads();
  for(int o=128;o>0;o>>=1){
    if(threadIdx.x<o) red[threadIdx.x] += red[threadIdx.x+o];
    __syncthreads();
  }
  if(threadIdx.x==0) gp[bc] = red[0]*(1.0f/HWs);
}

// ---------------- gating MLP (tiny) ----------------
__global__ __launch_bounds__(256) void gate_kernel(const float* __restrict__ gp,
    const float* __restrict__ g1w, const float* __restrict__ g1b,
    const float* __restrict__ g2w, const float* __restrict__ g2b,
    float* __restrict__ cwaw){
  __shared__ float h[NB][64];
  __shared__ float zz[NB][2];
  int t = threadIdx.x;
  int b = t >> 6, j = t & 63;
  const float* gpb = gp + b*DIMC;
  const float* wr  = g1w + j*DIMC;
  float s = g1b[j];
  for(int c=0;c<DIMC;c++) s += gpb[c]*wr[c];
  h[b][j] = fmaxf(s, 0.f);
  __syncthreads();
  if (t < 8){
    int b2 = t >> 1, o = t & 1;
    float z = g2b[o];
    const float* w2 = g2w + o*64;
    for(int q=0;q<64;q++) z += w2[q]*h[b2][q];
    zz[b2][o] = z;
  }
  __syncthreads();
  if (t < 4){
    float z0 = zz[t][0], z1 = zz[t][1];
    float mm = fmaxf(z0,z1);
    float e0 = __expf(z0-mm), e1 = __expf(z1-mm);
    float inv = 1.0f/(e0+e1);
    cwaw[2*t]   = e0*inv;
    cwaw[2*t+1] = e1*inv;
  }
}

// ---------------- depthwise conv 3x3 + 5x5, block-uniform channel ----------------
__global__ __launch_bounds__(256) void dwconv_kernel(const bf* __restrict__ y,
    const float* __restrict__ w3, const float* __restrict__ b3,
    const float* __restrict__ w5, const float* __restrict__ b5,
    bf* __restrict__ out){
  int bi = blockIdx.x;                 // 4*256*8
  int strip = bi & 7;
  int c  = (bi >> 3) & 255;
  int b  = bi >> 11;
  int t = threadIdx.x;
  int sx = t & 15, ry = t >> 4;
  int hy = strip*16 + ry;
  int x0 = sx << 3;
  const u16* pl = (const u16*)y + ((size_t)(b*DIMC + c))*HWs;

  float kc[25];
  #pragma unroll
  for(int i=0;i<25;i++) kc[i] = w5[c*25+i];
  #pragma unroll
  for(int di=0;di<3;di++)
    #pragma unroll
    for(int dj=0;dj<3;dj++)
      kc[(di+1)*5 + (dj+1)] += w3[c*9 + di*3 + dj];
  float bia = b3[c] + b5[c];

  float acc[8];
  #pragma unroll
  for(int j=0;j<8;j++) acc[j] = bia;

  #pragma unroll
  for(int di=-2; di<=2; di++){
    int yy = hy + di;
    float row[16];
    if ((unsigned)yy < 128u){
      const u16* rp = pl + yy*WW;
      uint2 z; z.x = 0u; z.y = 0u;
      uint2 c0 = (x0 > 0)   ? *(const uint2*)(rp + x0 - 4) : z;
      uint2 c1 = *(const uint2*)(rp + x0);
      uint2 c2 = *(const uint2*)(rp + x0 + 4);
      uint2 c3 = (x0 < 120) ? *(const uint2*)(rp + x0 + 8) : z;
      unp4(c0, row); unp4(c1, row+4); unp4(c2, row+8); unp4(c3, row+12);
    } else {
      #pragma unroll
      for(int j=0;j<16;j++) row[j] = 0.f;
    }
    #pragma unroll
    for(int dj=-2; dj<=2; dj++){
      float w = kc[(di+2)*5 + (dj+2)];
      #pragma unroll
      for(int j=0;j<8;j++) acc[j] += row[4+j+dj]*w;
    }
  }
  u32x4 res;
  #pragma unroll
  for(int q=0;q<4;q++) ((u32*)&res)[q] = pack2(acc[2*q], acc[2*q+1]);
  *(u32x4*)((u16*)out + ((size_t)(b*DIMC + c))*HWs + hy*WW + x0) = res;
}

// ---------------- grouped conv (2-2 per group, 3x3) + GLU, o-pair per thread ----------------
__global__ __launch_bounds__(256) void dwconv2_glu_kernel(const bf* __restrict__ p,
    const float* __restrict__ w, bf* __restrict__ m){
  int bi = blockIdx.x;                 // 4*128*8
  int strip = bi & 7;
  int op = (bi >> 3) & 127;
  int b  = bi >> 10;
  int o0 = op*2, o1 = o0+1;
  int t = threadIdx.x;
  int sx = t & 15, ry = t >> 4;
  int hy = strip*16 + ry;
  int x0 = sx << 3;
  const u16* p0 = (const u16*)p + ((size_t)b*C2 + o0)*HWs;
  const u16* p1 = p0 + HWs;
  const u16* p2 = p0 + (size_t)256*HWs;
  const u16* p3 = p2 + HWs;

  float KA0[9], KA1[9], KA2[9], KA3[9];
  float KB0[9], KB1[9], KB2[9], KB3[9];
  #pragma unroll
  for(int i=0;i<9;i++){
    KA0[i] = w[o0*18 + i];        KA1[i] = w[o0*18 + 9 + i];
    KA2[i] = w[(o0+256)*18 + i];  KA3[i] = w[(o0+256)*18 + 9 + i];
    KB0[i] = w[o1*18 + i];        KB1[i] = w[o1*18 + 9 + i];
    KB2[i] = w[(o1+256)*18 + i];  KB3[i] = w[(o1+256)*18 + 9 + i];
  }

  float a1A[8] = {}, a2A[8] = {}, a1B[8] = {}, a2B[8] = {};
  #pragma unroll
  for(int di=-1; di<=1; di++){
    int yy = hy + di;
    if ((unsigned)yy >= 128u) continue;
    int roff = yy*WW;
    float r0[16], r1[16], r2[16], r3[16];
    uint2 z; z.x = 0u; z.y = 0u;
    bool lo = (x0 > 0), hi = (x0 < 120);
    {
      const u16* rp = p0 + roff;
      uint2 c0 = lo ? *(const uint2*)(rp + x0 - 4) : z;
      uint2 c1 = *(const uint2*)(rp + x0);
      uint2 c2 = *(const uint2*)(rp + x0 + 4);
      uint2 c3 = hi ? *(const uint2*)(rp + x0 + 8) : z;
      unp4(c0, r0); unp4(c1, r0+4); unp4(c2, r0+8); unp4(c3, r0+12);
    }
    {
      const u16* rp = p1 + roff;
      uint2 c0 = lo ? *(const uint2*)(rp + x0 - 4) : z;
      uint2 c1 = *(const uint2*)(rp + x0);
      uint2 c2 = *(const uint2*)(rp + x0 + 4);
      uint2 c3 = hi ? *(const uint2*)(rp + x0 + 8) : z;
      unp4(c0, r1); unp4(c1, r1+4); unp4(c2, r1+8); unp4(c3, r1+12);
    }
    {
      const u16* rp = p2 + roff;
      uint2 c0 = lo ? *(const uint2*)(rp + x0 - 4) : z;
      uint2 c1 = *(const uint2*)(rp + x0);
      uint2 c2 = *(const uint2*)(rp + x0 + 4);
      uint2 c3 = hi ? *(const uint2*)(rp + x0 + 8) : z;
      unp4(c0, r2); unp4(c1, r2+4); unp4(c2, r2+8); unp4(c3, r2+12);
    }
    {
      const u16* rp = p3 + roff;
      uint2 c0 = lo ? *(const uint2*)(rp + x0 - 4) : z;
      uint2 c1 = *(const uint2*)(rp + x0);
      uint2 c2 = *(const uint2*)(rp + x0 + 4);
      uint2 c3 = hi ? *(const uint2*)(rp + x0 + 8) : z;
      unp4(c0, r3); unp4(c1, r3+4); unp4(c2, r3+8); unp4(c3, r3+12);
    }
    #pragma unroll
    for(int dj=-1; dj<=1; dj++){
      int ki = (di+1)*3 + (dj+1);
      #pragma unroll
      for(int j=0;j<8;j++){
        int ii = 4+j+dj;
        a1A[j] += r0[ii]*KA0[ki] + r1[ii]*KA1[ki];
        a2A[j] += r2[ii]*KA2[ki] + r3[ii]*KA3[ki];
        a1B[j] += r0[ii]*KB0[ki] + r1[ii]*KB1[ki];
        a2B[j] += r2[ii]*KB2[ki] + r3[ii]*KB3[ki];
      }
    }
  }
  size_t obase = ((size_t)(b*DIMC + o0))*HWs + hy*WW + x0;
  u32x4 resA, resB;
  #pragma unroll
  for(int q=0;q<4;q++){
    ((u32*)&resA)[q] = pack2(gelu_exact(a1A[2*q])*a2A[2*q],
                             gelu_exact(a1A[2*q+1])*a2A[2*q+1]);
    ((u32*)&resB)[q] = pack2(gelu_exact(a1B[2*q])*a2B[2*q],
                             gelu_exact(a1B[2*q+1])*a2B[2*q+1]);
  }
  *(u32x4*)((u16*)m + obase) = resA;
  *(u32x4*)((u16*)m + obase + HWs) = resB;
}

// ---------------- bf16 MFMA GEMM, A+B via LDS, 4 blocks/CU, XCD-grouped tiles ----------------
// 1-D grid, nwg = 512*NY. bid = xcd + 8*local; x = xcd + 8*(local/NY); y = local%NY.
// All NY o-tiles of one pixel tile share bid%8 -> same XCD -> B panel L2-resident.
template<int NY, typename TRES, typename TOUT>
__global__ __launch_bounds__(256, 4) void mfma_gemm(
    const u16* __restrict__ Wb, const bf* __restrict__ act,
    const float* __restrict__ bias, const TRES* __restrict__ resid,
    TOUT* __restrict__ out, int Oc)
{
  __shared__ u16 As[2][4608];     // [128][36]
  __shared__ u16 Bs[2][4096];     // [128][32]
  int t  = threadIdx.x;
  int bid = blockIdx.x;
  int xcd = bid & 7;
  int local = bid >> 3;
  int xg = xcd + 8*(local / NY);
  int yg = local % NY;
  int n0 = xg * 128;
  int o0 = yg * 128;
  int b  = n0 >> 14;
  int sp = n0 & (HWs-1);
  const u16* actu = (const u16*)act + (size_t)b*256*HWs + sp;

  int kp = t & 15;
  int ns = (t >> 4) << 3;
  int lane = t & 63;
  int wv = t >> 6;
  int wr = (wv >> 1) << 6;
  int wc = (wv & 1) << 6;
  int fr = lane & 15;
  int kg = lane >> 4;
  int arow = t >> 1;
  int ahalf = (t & 1) << 4;

  f32x4 acc[4][4] = {};

  auto loadB = [&](int ks, u32x4& u, u32x4& v){
    const u16* r0 = actu + (size_t)(ks*32 + 2*kp)*HWs + ns;
    u = *(const u32x4*)r0;
    v = *(const u32x4*)(r0 + HWs);
  };
  auto writeB = [&](const u32x4& u, const u32x4& v, int buf){
    u32 w0=(u.x&0xffffu)|(v.x<<16), w1=(u.x>>16)|(v.x&0xffff0000u);
    u32 w2=(u.y&0xffffu)|(v.y<<16), w3=(u.y>>16)|(v.y&0xffff0000u);
    u32 w4=(u.z&0xffffu)|(v.z<<16), w5=(u.z>>16)|(v.z&0xffff0000u);
    u32 w6=(u.w&0xffffu)|(v.w<<16), w7=(u.w>>16)|(v.w&0xffff0000u);
    u16* bp = Bs[buf];
    int c0 = kp*2;
    *(u32*)&bp[(ns+0)*32+c0]=w0; *(u32*)&bp[(ns+1)*32+c0]=w1;
    *(u32*)&bp[(ns+2)*32+c0]=w2; *(u32*)&bp[(ns+3)*32+c0]=w3;
    *(u32*)&bp[(ns+4)*32+c0]=w4; *(u32*)&bp[(ns+5)*32+c0]=w5;
    *(u32*)&bp[(ns+6)*32+c0]=w6; *(u32*)&bp[(ns+7)*32+c0]=w7;
  };
  auto loadA = [&](int ks, u32x4& a0, u32x4& a1){
    const u16* ap = Wb + (size_t)(o0+arow)*256 + ks*32 + ahalf;
    a0 = *(const u32x4*)ap;
    a1 = *(const u32x4*)(ap + 8);
  };
  auto writeA = [&](const u32x4& a0, const u32x4& a1, int buf){
    u16* dst = &As[buf][arow*36 + ahalf];
    *(u32x4*)dst = a0;
    *(u32x4*)(dst+8) = a1;
  };

  {
    u32x4 bu, bvv, a0, a1;
    loadB(0, bu, bvv); loadA(0, a0, a1);
    writeB(bu, bvv, 0); writeA(a0, a1, 0);
  }
  #pragma unroll
  for(int ks=0; ks<8; ++ks){
    int cur = ks & 1;
    __syncthreads();
    u32x4 bu, bvv, a0, a1;
    if (ks < 7){ loadB(ks+1, bu, bvv); loadA(ks+1, a0, a1); }
    bf16x8 af[4], bfr[4];
    #pragma unroll
    for(int j=0;j<4;j++)
      bfr[j] = *(const bf16x8*)&Bs[cur][(wc + j*16 + fr)*32 + kg*8];
    #pragma unroll
    for(int i=0;i<4;i++)
      af[i] = *(const bf16x8*)&As[cur][(wr + i*16 + fr)*36 + kg*8];
    #pragma unroll
    for(int i=0;i<4;i++)
      #pragma unroll
      for(int j=0;j<4;j++)
        acc[i][j] = __builtin_amdgcn_mfma_f32_16x16x32_bf16(af[i], bfr[j], acc[i][j], 0, 0, 0);
    if (ks < 7){ writeB(bu, bvv, cur^1); writeA(a0, a1, cur^1); }
  }

  #pragma unroll
  for(int i=0;i<4;i++){
    #pragma unroll
    for(int reg=0;reg<4;reg++){
      int o = o0 + wr + i*16 + kg*4 + reg;
      size_t rowoff = ((size_t)b*Oc + o)*HWs + sp + wc + fr;
      float bia = bias ? bias[o] : 0.f;
      #pragma unroll
      for(int j=0;j<4;j++){
        float val = acc[i][j][reg] + bia;
        size_t pidx = rowoff + (size_t)(j*16);
        if (resid) val += ldf(resid + pidx);
        sto(out + pidx, val);
      }
    }
  }
}

// [128 rows][128 bf16] LDS plane swizzle: 16B-chunk XOR by row&7 + row-bit3 half-flip
#define SWB(r,c2) ((r)*256 + ((c2) ^ ((((r)&7)<<4)) ^ ((((r)>>3)&1)<<6)))

// ---------------- MFMA axial attention (R11 verbatim — proven 85us) ----------------
__global__ __launch_bounds__(256, 2) void attn_mfma(const bf* __restrict__ qkv,
    const float* __restrict__ scale, bf* __restrict__ outp,
    const bf* __restrict__ conv, const float* __restrict__ cwaw){
  __shared__ u16 LB0[16384];
  __shared__ u16 LB1[16384];
  __shared__ float2 red2[4];
  int s  = blockIdx.x;
  int b  = s >> 8;
  int ch = s & 255;
  const u16* qp = (const u16*)qkv + ((size_t)b*768 + ch)*HWs;
  const u16* kp = qp + (size_t)256*HWs;
  const u16* vp = qp + (size_t)512*HWs;
  int t = threadIdx.x;

  int lane = t & 63, wvi = t >> 6;
  int fr = lane & 15, kg = lane >> 4;
  int nb = wvi << 5;
  int rr = t >> 1, hb = (t & 1) << 7;
  int kp2 = (t & 15)*2, cs = (t >> 4) << 3;

  auto nat_load = [&](const u16* src, u32x4* R){
    #pragma unroll
    for(int i=0;i<8;i++)
      R[i] = *(const u32x4*)((const char*)src + rr*256 + hb + i*16);
  };
  auto nat_write = [&](const u32x4* R, u16* dst){
    #pragma unroll
    for(int i=0;i<8;i++)
      *(u32x4*)((char*)dst + SWB(rr, hb + i*16)) = R[i];
  };
  auto nat_write_sum = [&](const u32x4* R, u16* dst) -> float {
    float ssum = 0.f;
    #pragma unroll
    for(int i=0;i<8;i++){
      *(u32x4*)((char*)dst + SWB(rr, hb + i*16)) = R[i];
      #pragma unroll
      for(int q=0;q<4;q++){
        float a0, a1;
        unpack2(((const u32*)&R[i])[q], a0, a1);
        ssum += a0*a0 + a1*a1;
      }
    }
    return ssum;
  };
  auto tr_load = [&](const u16* src, u32x4* R){
    #pragma unroll
    for(int bi=0;bi<4;bi++){
      int sr = bi*32 + kp2;
      R[2*bi]   = *(const u32x4*)(src + sr*128 + cs);
      R[2*bi+1] = *(const u32x4*)(src + (sr+1)*128 + cs);
    }
  };
  auto tr_load_lds = [&](const u16* lb, u32x4* R){
    #pragma unroll
    for(int bi=0;bi<4;bi++){
      int sr = bi*32 + kp2;
      R[2*bi]   = *(const u32x4*)((const char*)lb + SWB(sr,   cs*2));
      R[2*bi+1] = *(const u32x4*)((const char*)lb + SWB(sr+1, cs*2));
    }
  };
  auto tr_write = [&](const u32x4* R, u16* dst){
    #pragma unroll
    for(int bi=0;bi<4;bi++){
      int sr = bi*32 + kp2;
      #pragma unroll
      for(int j=0;j<8;j++){
        u32 uw = ((const u32*)&R[2*bi])[j>>1];
        u32 vw = ((const u32*)&R[2*bi+1])[j>>1];
        u32 wv = (j&1) ? ((uw>>16) | (vw & 0xffff0000u))
                       : ((uw & 0xffffu) | (vw<<16));
        *(u32*)((char*)dst + SWB(cs+j, sr*2)) = wv;
      }
    }
  };

  f32x4 acc[8][2];
  f32x4 oacc[8][2];
  const f32x4 vzero = {};
  float ls = 0.f;

  auto mmloop = [&](const u16* afsrc, const u16* bfsrc, f32x4 (&A)[8][2]){
    #pragma unroll
    for(int kk=0;kk<128;kk+=32){
      int kb2 = kk*2 + kg*16;
      bf16x8 b0 = *(const bf16x8*)((const char*)bfsrc + SWB(nb+fr,    kb2));
      bf16x8 b1 = *(const bf16x8*)((const char*)bfsrc + SWB(nb+16+fr, kb2));
      #pragma unroll
      for(int mt=0;mt<8;mt++){
        bf16x8 a0 = *(const bf16x8*)((const char*)afsrc + SWB(mt*16+fr, kb2));
        A[mt][0] = __builtin_amdgcn_mfma_f32_16x16x32_bf16(a0, b0, A[mt][0], 0, 0, 0);
        A[mt][1] = __builtin_amdgcn_mfma_f32_16x16x32_bf16(a0, b1, A[mt][1], 0, 0, 0);
      }
    }
  };

  auto writeCT = [&](u16* dst, f32x4 (&A)[8][2]){
    #pragma unroll
    for(int nt=0;nt<2;nt++){
      int n = nb + nt*16 + fr;
      #pragma unroll
      for(int mt=0;mt<8;mt++){
        #pragma unroll
        for(int pr=0;pr<2;pr++){
          u32 wv = pack2(A[mt][nt][pr*2], A[mt][nt][pr*2+1]);
          int z2 = (mt*16 + kg*4 + pr*2)*2;
          *(u32*)((char*)dst + SWB(n, z2)) = wv;
        }
      }
    }
  };

  auto softmax = [&](){
    #pragma unroll
    for(int nt=0;nt<2;nt++){
      float mx = -1e30f;
      #pragma unroll
      for(int mt=0;mt<8;mt++)
        #pragma unroll
        for(int rg=0;rg<4;rg++){
          acc[mt][nt][rg] *= ls;
          mx = fmaxf(mx, acc[mt][nt][rg]);
        }
      mx = fmaxf(mx, __shfl_xor(mx,16));
      mx = fmaxf(mx, __shfl_xor(mx,32));
      float sm = 0.f;
      #pragma unroll
      for(int mt=0;mt<8;mt++)
        #pragma unroll
        for(int rg=0;rg<4;rg++){
          float e = __expf(acc[mt][nt][rg]-mx);
          acc[mt][nt][rg] = e; sm += e;
        }
      sm += __shfl_xor(sm,16);
      sm += __shfl_xor(sm,32);
      float inv = 1.0f/sm;
      #pragma unroll
      for(int mt=0;mt<8;mt++)
        #pragma unroll
        for(int rg=0;rg<4;rg++)
          acc[mt][nt][rg] *= inv;
    }
  };

  u32x4 RK[8], RQ[8], RV[8];

  // phase 0: K,Q,V global loads in flight; stage K,Q nat (+lscale sums)
  nat_load(kp, RK);
  nat_load(qp, RQ);
  tr_load(vp, RV);                         // V^T; hides under phase 1
  float sk = nat_write_sum(RK, LB0);
  float sq = nat_write_sum(RQ, LB1);
  #pragma unroll
  for(int off=1; off<64; off<<=1){
    sq += __shfl_xor(sq, off);
    sk += __shfl_xor(sk, off);
  }
  if (lane == 0) red2[wvi] = make_float2(sq, sk);
  __syncthreads();
  {
    float tq = 0.f, tk = 0.f;
    #pragma unroll
    for(int wI=0;wI<4;wI++){ tq += red2[wI].x; tk += red2[wI].y; }
    float nq = fmaxf(sqrtf(tq), 1e-12f);
    float nk = fmaxf(sqrtf(tk), 1e-12f);
    ls = scale[ch & 15] / (nq*nk);
  }

  // phase 1: S0^T + softmax; then pull K^T,Q^T register tiles FROM LDS
  #pragma unroll
  for(int mt=0;mt<8;mt++){ acc[mt][0]=vzero; acc[mt][1]=vzero; }
  mmloop(LB0, LB1, acc);
  softmax();
  tr_load_lds(LB0, RK);                    // K nat still in LB0
  tr_load_lds(LB1, RQ);                    // Q nat still in LB1
  __syncthreads();

  // phase 2: P->LB0, V^T->LB1
  writeCT(LB0, acc);
  tr_write(RV, LB1);
  __syncthreads();

  // phase 3: O0 (A=V^T, B=P)
  #pragma unroll
  for(int mt=0;mt<8;mt++){ oacc[mt][0]=vzero; oacc[mt][1]=vzero; }
  mmloop(LB1, LB0, oacc);
  __syncthreads();

  // phase 4: K^T->LB0, Q^T->LB1; V nat global load issued
  tr_write(RK, LB0);
  tr_write(RQ, LB1);
  nat_load(vp, RV);                        // hides under phase 5
  __syncthreads();

  // phase 5: S1^T + softmax
  #pragma unroll
  for(int mt=0;mt<8;mt++){ acc[mt][0]=vzero; acc[mt][1]=vzero; }
  mmloop(LB0, LB1, acc);
  softmax();
  __syncthreads();

  // phase 6: P->LB0, V->LB1; conv loads issued
  writeCT(LB0, acc);
  nat_write(RV, LB1);
  const u16* cp = (const u16*)conv + ((size_t)b*DIMC + ch)*HWs;
  u32x4 RC[8];
  #pragma unroll
  for(int i=0;i<8;i++)
    RC[i] = *(const u32x4*)(cp + rr*128 + (hb>>1) + i*8);  // hides under phase 7
  __syncthreads();

  // phase 7: O1 accumulates (A=P, B=V)
  mmloop(LB0, LB1, oacc);
  __syncthreads();

  // phase 8: O -> LB0 spatial [h][w]
  writeCT(LB0, oacc);
  __syncthreads();

  // phase 9: copy-out with conv mix
  float cw = cwaw[2*b], aw = cwaw[2*b+1];
  bf* op = outp + ((size_t)b*DIMC + ch)*HWs;
  #pragma unroll
  for(int i=0;i<8;i++){
    int c2 = hb + i*16;
    u32x4 ov = *(const u32x4*)((char*)LB0 + SWB(rr, c2));
    u32x4 res;
    #pragma unroll
    for(int q=0;q<4;q++){
      float o0,o1,c0,c1;
      unpack2(((u32*)&ov)[q], o0, o1);
      unpack2(((const u32*)&RC[i])[q], c0, c1);
      ((u32*)&res)[q] = pack2(cw*c0 + aw*o0, cw*c1 + aw*o1);
    }
    *(u32x4*)((u16*)op + rr*128 + (hb>>1) + i*8) = res;
  }
}

// ---------------- launch ----------------
extern "C" void kernel_launch(void* const* d_in, const int* in_sizes, int n_in,
                              void* d_out, int out_size, void* d_ws, size_t ws_size,
                              hipStream_t stream){
  (void)in_sizes; (void)n_in; (void)out_size; (void)ws_size;
  const float* x       = (const float*)d_in[0];
  const float* ln1_w   = (const float*)d_in[1];
  const float* ln1_b   = (const float*)d_in[2];
  const float* conv3_w = (const float*)d_in[3];
  const float* conv3_b = (const float*)d_in[4];
  const float* conv5_w = (const float*)d_in[5];
  const float* conv5_b = (const float*)d_in[6];
  const float* qkv_w   = (const float*)d_in[7];
  const float* scale   = (const float*)d_in[8];
  const float* g1_w    = (const float*)d_in[9];
  const float* g1_b    = (const float*)d_in[10];
  const float* g2_w    = (const float*)d_in[11];
  const float* g2_b    = (const float*)d_in[12];
  const float* proj_w  = (const float*)d_in[13];
  const float* proj_b  = (const float*)d_in[14];
  const float* ln2_w   = (const float*)d_in[15];
  const float* ln2_b   = (const float*)d_in[16];
  const float* pin_w   = (const float*)d_in[17];
  const float* dw_w    = (const float*)d_in[18];
  const float* pout_w  = (const float*)d_in[19];
  float* out = (float*)d_out;
  char* wsb  = (char*)d_ws;

  const size_t MB = 1024*1024;
  bf* y    = (bf*)(wsb +   0*MB);
  bf* conv = (bf*)(wsb +  32*MB);
  bf* qkv  = (bf*)(wsb +  64*MB);
  bf* attnf= (bf*)(wsb +   0*MB);
  bf* xnew = (bf*)(wsb +  64*MB);
  bf* y2   = (bf*)(wsb +  96*MB);
  bf* p    = (bf*)(wsb +   0*MB);
  bf* m    = (bf*)(wsb +  96*MB);
  u16* Wqkv  = (u16*)(wsb + 160*MB);
  u16* Wproj = Wqkv + 196608;
  u16* Wpin  = Wproj + 65536;
  u16* Wpout = Wpin + 131072;
  float* gp     = (float*)(Wpout + 65536);
  float* cwaw   = gp + 1024;

  cvt_all_kernel<<<1792,256,0,stream>>>(qkv_w, proj_w, pin_w, pout_w,
                                        Wqkv, Wproj, Wpin, Wpout,
                                        196608, 65536, 131072, 65536);

  ln1_2px_kernel<<<128,256,0,stream>>>(x, ln1_w, ln1_b, y);
  gp_kernel<<<1024,256,0,stream>>>(y, gp);
  gate_kernel<<<1,256,0,stream>>>(gp, g1_w, g1_b, g2_w, g2_b, cwaw);
  dwconv_kernel<<<8192,256,0,stream>>>(y, conv3_w, conv3_b, conv5_w, conv5_b, conv);
  mfma_gemm<6,float,bf><<<3072,256,0,stream>>>(Wqkv, y, nullptr,
                                        (const float*)nullptr, qkv, 768);
  attn_mfma<<<1024,256,0,stream>>>(qkv, scale, attnf, conv, cwaw);
  mfma_gemm<2,float,bf><<<1024,256,0,stream>>>(Wproj, attnf, proj_b, x, xnew, 256);
  ln2px_kernel<<<128,256,0,stream>>>(xnew, ln2_w, ln2_b, y2);
  mfma_gemm<4,float,bf><<<2048,256,0,stream>>>(Wpin, y2, nullptr,
                                        (const float*)nullptr, p, 512);
  dwconv2_glu_kernel<<<4096,256,0,stream>>>(p, dw_w, m);
  mfma_gemm<2,bf,float><<<1024,256,0,stream>>>(Wpout, m, nullptr, xnew, out, 256);
}

// Round 16
// 403.441 us; speedup vs baseline: 1.0880x; 1.0880x over previous
//
#include <hip/hip_runtime.h>
#include <hip/hip_bf16.h>
#include <math.h>

#define DIMC 256
#define NB   4
#define HH   128
#define WW   128
#define HWs  16384
#define HID  256
#define C2   512
#define EPSf 1e-5f

typedef __hip_bfloat16 bf;
typedef unsigned short u16;
typedef unsigned int   u32;
typedef float f32x4  __attribute__((ext_vector_type(4)));
typedef u32   u32x4  __attribute__((ext_vector_type(4)));
typedef short bf16x8 __attribute__((ext_vector_type(8)));

__device__ __forceinline__ float b2f(bf v){ return __bfloat162float(v); }
__device__ __forceinline__ bf    f2b(float v){ return __float2bfloat16(v); }
__device__ __forceinline__ float ldf(const float* p){ return *p; }
__device__ __forceinline__ float ldf(const bf* p){ return __bfloat162float(*p); }
__device__ __forceinline__ void  sto(float* p, float v){ *p = v; }
__device__ __forceinline__ void  sto(bf* p, float v){ *p = f2b(v); }
__device__ __forceinline__ void unpack2(u32 u, float& a, float& b){
  union{u32 x; float f;} lo, hi;
  lo.x = u << 16; hi.x = u & 0xffff0000u;
  a = lo.f; b = hi.f;
}
__device__ __forceinline__ u32 pack2(float a, float b){
  bf h0 = f2b(a), h1 = f2b(b);
  return (u32)*(u16*)&h0 | ((u32)*(u16*)&h1 << 16);
}
__device__ __forceinline__ void unp4(uint2 u, float* d){
  unpack2(u.x, d[0], d[1]); unpack2(u.y, d[2], d[3]);
}

__device__ __forceinline__ float gelu_exact(float v){
  return 0.5f*v*(1.0f + erff(v*0.70710678118654752f));
}

// ---------------- merged weight fp32 -> bf16 convert (one launch) ----------------
__global__ __launch_bounds__(256) void cvt_all_kernel(
    const float* __restrict__ s0, const float* __restrict__ s1,
    const float* __restrict__ s2, const float* __restrict__ s3,
    u16* __restrict__ d0, u16* __restrict__ d1,
    u16* __restrict__ d2, u16* __restrict__ d3,
    int n0, int n1, int n2, int n3){
  int i = blockIdx.x*256 + threadIdx.x;
  if (i < n0){ bf h = f2b(s0[i]); d0[i] = *(u16*)&h; return; }
  i -= n0;
  if (i < n1){ bf h = f2b(s1[i]); d1[i] = *(u16*)&h; return; }
  i -= n1;
  if (i < n2){ bf h = f2b(s2[i]); d2[i] = *(u16*)&h; return; }
  i -= n2;
  if (i < n3){ bf h = f2b(s3[i]); d3[i] = *(u16*)&h; }
}

// ---------------- LayerNorm over channel dim (per pixel), fp32 in, bf16 out ----------------
__global__ __launch_bounds__(256) void ln_kernel(const float* __restrict__ x,
    const float* __restrict__ w, const float* __restrict__ bb, bf* __restrict__ y){
  int p = blockIdx.x*256 + threadIdx.x;
  int b  = p >> 14;
  int sp = p & (HWs-1);
  const float* xb = x + (size_t)b*DIMC*HWs + sp;
  float s = 0.f, s2 = 0.f;
  for(int c=0;c<DIMC;c++){ float v = xb[(size_t)c*HWs]; s += v; s2 += v*v; }
  float mu   = s * (1.0f/DIMC);
  float var  = s2 * (1.0f/DIMC) - mu*mu;
  float rinv = rsqrtf(var + EPSf);
  bf* yb = y + (size_t)b*DIMC*HWs + sp;
  for(int c=0;c<DIMC;c++){
    float v = xb[(size_t)c*HWs];
    yb[(size_t)c*HWs] = f2b((v - mu)*rinv*w[c] + bb[c]);
  }
}

// ---------------- LayerNorm, bf16 in, 2 pixels/thread (packed u32 I/O) ----------------
__global__ __launch_bounds__(256) void ln2px_kernel(const bf* __restrict__ x,
    const float* __restrict__ w, const float* __restrict__ bb, bf* __restrict__ y){
  int p2 = blockIdx.x*256 + threadIdx.x;   // pixel pair id, 0..NPIX/2-1
  int b  = p2 >> 13;                        // 8192 pairs per batch
  int sp = (p2 & 8191) << 1;
  const u16* xb = (const u16*)x + (size_t)b*DIMC*HWs + sp;
  float s0=0.f, s1=0.f, q0=0.f, q1=0.f;
  for(int c=0;c<DIMC;c++){
    u32 u = *(const u32*)(xb + (size_t)c*HWs);
    float a0, a1; unpack2(u, a0, a1);
    s0 += a0; q0 += a0*a0;
    s1 += a1; q1 += a1*a1;
  }
  float mu0 = s0*(1.0f/DIMC), mu1 = s1*(1.0f/DIMC);
  float r0 = rsqrtf(q0*(1.0f/DIMC) - mu0*mu0 + EPSf);
  float r1 = rsqrtf(q1*(1.0f/DIMC) - mu1*mu1 + EPSf);
  u16* yb = (u16*)y + (size_t)b*DIMC*HWs + sp;
  for(int c=0;c<DIMC;c++){
    u32 u = *(const u32*)(xb + (size_t)c*HWs);
    float a0, a1; unpack2(u, a0, a1);
    float wc = w[c], bc = bb[c];
    *(u32*)(yb + (size_t)c*HWs) = pack2((a0-mu0)*r0*wc + bc, (a1-mu1)*r1*wc + bc);
  }
}

// ---------------- global average pool per (b,c), vectorized ----------------
__global__ __launch_bounds__(256) void gp_kernel(const bf* __restrict__ y, float* __restrict__ gp){
  int bc = blockIdx.x;
  const u32x4* pl = (const u32x4*)(y + (size_t)bc*HWs);   // 2048 vec8 elems
  float s = 0.f;
  for(int i=threadIdx.x;i<2048;i+=256){
    u32x4 v = pl[i];
    #pragma unroll
    for(int q=0;q<4;q++){
      float a0, a1; unpack2(((const u32*)&v)[q], a0, a1);
      s += a0 + a1;
    }
  }
  __shared__ float red[256];
  red[threadIdx.x] = s; __syncthreads();
  for(int o=128;o>0;o>>=1){
    if(threadIdx.x<o) red[threadIdx.x] += red[threadIdx.x+o];
    __syncthreads();
  }
  if(threadIdx.x==0) gp[bc] = red[0]*(1.0f/HWs);
}

// ---------------- gating MLP (tiny) ----------------
__global__ __launch_bounds__(256) void gate_kernel(const float* __restrict__ gp,
    const float* __restrict__ g1w, const float* __restrict__ g1b,
    const float* __restrict__ g2w, const float* __restrict__ g2b,
    float* __restrict__ cwaw){
  __shared__ float h[NB][64];
  __shared__ float zz[NB][2];
  int t = threadIdx.x;
  int b = t >> 6, j = t & 63;
  const float* gpb = gp + b*DIMC;
  const float* wr  = g1w + j*DIMC;
  float s = g1b[j];
  for(int c=0;c<DIMC;c++) s += gpb[c]*wr[c];
  h[b][j] = fmaxf(s, 0.f);
  __syncthreads();
  if (t < 8){
    int b2 = t >> 1, o = t & 1;
    float z = g2b[o];
    const float* w2 = g2w + o*64;
    for(int q=0;q<64;q++) z += w2[q]*h[b2][q];
    zz[b2][o] = z;
  }
  __syncthreads();
  if (t < 4){
    float z0 = zz[t][0], z1 = zz[t][1];
    float mm = fmaxf(z0,z1);
    float e0 = __expf(z0-mm), e1 = __expf(z1-mm);
    float inv = 1.0f/(e0+e1);
    cwaw[2*t]   = e0*inv;
    cwaw[2*t+1] = e1*inv;
  }
}

// ---------------- depthwise conv 3x3 + 5x5, block-uniform channel ----------------
__global__ __launch_bounds__(256) void dwconv_kernel(const bf* __restrict__ y,
    const float* __restrict__ w3, const float* __restrict__ b3,
    const float* __restrict__ w5, const float* __restrict__ b5,
    bf* __restrict__ out){
  int bi = blockIdx.x;                 // 4*256*8
  int strip = bi & 7;
  int c  = (bi >> 3) & 255;
  int b  = bi >> 11;
  int t = threadIdx.x;
  int sx = t & 15, ry = t >> 4;
  int hy = strip*16 + ry;
  int x0 = sx << 3;
  const u16* pl = (const u16*)y + ((size_t)(b*DIMC + c))*HWs;

  float kc[25];
  #pragma unroll
  for(int i=0;i<25;i++) kc[i] = w5[c*25+i];
  #pragma unroll
  for(int di=0;di<3;di++)
    #pragma unroll
    for(int dj=0;dj<3;dj++)
      kc[(di+1)*5 + (dj+1)] += w3[c*9 + di*3 + dj];
  float bia = b3[c] + b5[c];

  float acc[8];
  #pragma unroll
  for(int j=0;j<8;j++) acc[j] = bia;

  #pragma unroll
  for(int di=-2; di<=2; di++){
    int yy = hy + di;
    float row[16];
    if ((unsigned)yy < 128u){
      const u16* rp = pl + yy*WW;
      uint2 z; z.x = 0u; z.y = 0u;
      uint2 c0 = (x0 > 0)   ? *(const uint2*)(rp + x0 - 4) : z;
      uint2 c1 = *(const uint2*)(rp + x0);
      uint2 c2 = *(const uint2*)(rp + x0 + 4);
      uint2 c3 = (x0 < 120) ? *(const uint2*)(rp + x0 + 8) : z;
      unp4(c0, row); unp4(c1, row+4); unp4(c2, row+8); unp4(c3, row+12);
    } else {
      #pragma unroll
      for(int j=0;j<16;j++) row[j] = 0.f;
    }
    #pragma unroll
    for(int dj=-2; dj<=2; dj++){
      float w = kc[(di+2)*5 + (dj+2)];
      #pragma unroll
      for(int j=0;j<8;j++) acc[j] += row[4+j+dj]*w;
    }
  }
  u32x4 res;
  #pragma unroll
  for(int q=0;q<4;q++) ((u32*)&res)[q] = pack2(acc[2*q], acc[2*q+1]);
  *(u32x4*)((u16*)out + ((size_t)(b*DIMC + c))*HWs + hy*WW + x0) = res;
}

// ---------------- grouped conv (2-2 per group, 3x3) + GLU, o-pair per thread ----------------
__global__ __launch_bounds__(256) void dwconv2_glu_kernel(const bf* __restrict__ p,
    const float* __restrict__ w, bf* __restrict__ m){
  int bi = blockIdx.x;                 // 4*128*8
  int strip = bi & 7;
  int op = (bi >> 3) & 127;
  int b  = bi >> 10;
  int o0 = op*2, o1 = o0+1;
  int t = threadIdx.x;
  int sx = t & 15, ry = t >> 4;
  int hy = strip*16 + ry;
  int x0 = sx << 3;
  const u16* p0 = (const u16*)p + ((size_t)b*C2 + o0)*HWs;
  const u16* p1 = p0 + HWs;
  const u16* p2 = p0 + (size_t)256*HWs;
  const u16* p3 = p2 + HWs;

  float KA0[9], KA1[9], KA2[9], KA3[9];
  float KB0[9], KB1[9], KB2[9], KB3[9];
  #pragma unroll
  for(int i=0;i<9;i++){
    KA0[i] = w[o0*18 + i];        KA1[i] = w[o0*18 + 9 + i];
    KA2[i] = w[(o0+256)*18 + i];  KA3[i] = w[(o0+256)*18 + 9 + i];
    KB0[i] = w[o1*18 + i];        KB1[i] = w[o1*18 + 9 + i];
    KB2[i] = w[(o1+256)*18 + i];  KB3[i] = w[(o1+256)*18 + 9 + i];
  }

  float a1A[8] = {}, a2A[8] = {}, a1B[8] = {}, a2B[8] = {};
  #pragma unroll
  for(int di=-1; di<=1; di++){
    int yy = hy + di;
    if ((unsigned)yy >= 128u) continue;
    int roff = yy*WW;
    float r0[16], r1[16], r2[16], r3[16];
    uint2 z; z.x = 0u; z.y = 0u;
    bool lo = (x0 > 0), hi = (x0 < 120);
    {
      const u16* rp = p0 + roff;
      uint2 c0 = lo ? *(const uint2*)(rp + x0 - 4) : z;
      uint2 c1 = *(const uint2*)(rp + x0);
      uint2 c2 = *(const uint2*)(rp + x0 + 4);
      uint2 c3 = hi ? *(const uint2*)(rp + x0 + 8) : z;
      unp4(c0, r0); unp4(c1, r0+4); unp4(c2, r0+8); unp4(c3, r0+12);
    }
    {
      const u16* rp = p1 + roff;
      uint2 c0 = lo ? *(const uint2*)(rp + x0 - 4) : z;
      uint2 c1 = *(const uint2*)(rp + x0);
      uint2 c2 = *(const uint2*)(rp + x0 + 4);
      uint2 c3 = hi ? *(const uint2*)(rp + x0 + 8) : z;
      unp4(c0, r1); unp4(c1, r1+4); unp4(c2, r1+8); unp4(c3, r1+12);
    }
    {
      const u16* rp = p2 + roff;
      uint2 c0 = lo ? *(const uint2*)(rp + x0 - 4) : z;
      uint2 c1 = *(const uint2*)(rp + x0);
      uint2 c2 = *(const uint2*)(rp + x0 + 4);
      uint2 c3 = hi ? *(const uint2*)(rp + x0 + 8) : z;
      unp4(c0, r2); unp4(c1, r2+4); unp4(c2, r2+8); unp4(c3, r2+12);
    }
    {
      const u16* rp = p3 + roff;
      uint2 c0 = lo ? *(const uint2*)(rp + x0 - 4) : z;
      uint2 c1 = *(const uint2*)(rp + x0);
      uint2 c2 = *(const uint2*)(rp + x0 + 4);
      uint2 c3 = hi ? *(const uint2*)(rp + x0 + 8) : z;
      unp4(c0, r3); unp4(c1, r3+4); unp4(c2, r3+8); unp4(c3, r3+12);
    }
    #pragma unroll
    for(int dj=-1; dj<=1; dj++){
      int ki = (di+1)*3 + (dj+1);
      #pragma unroll
      for(int j=0;j<8;j++){
        int ii = 4+j+dj;
        a1A[j] += r0[ii]*KA0[ki] + r1[ii]*KA1[ki];
        a2A[j] += r2[ii]*KA2[ki] + r3[ii]*KA3[ki];
        a1B[j] += r0[ii]*KB0[ki] + r1[ii]*KB1[ki];
        a2B[j] += r2[ii]*KB2[ki] + r3[ii]*KB3[ki];
      }
    }
  }
  size_t obase = ((size_t)(b*DIMC + o0))*HWs + hy*WW + x0;
  u32x4 resA, resB;
  #pragma unroll
  for(int q=0;q<4;q++){
    ((u32*)&resA)[q] = pack2(gelu_exact(a1A[2*q])*a2A[2*q],
                             gelu_exact(a1A[2*q+1])*a2A[2*q+1]);
    ((u32*)&resB)[q] = pack2(gelu_exact(a1B[2*q])*a2B[2*q],
                             gelu_exact(a1B[2*q+1])*a2B[2*q+1]);
  }
  *(u32x4*)((u16*)m + obase) = resA;
  *(u32x4*)((u16*)m + obase + HWs) = resB;
}

// ---------------- bf16 MFMA GEMM, A+B through double-buffered LDS, 4 blocks/CU ----------------
template<typename TRES, typename TOUT>
__global__ __launch_bounds__(256, 4) void mfma_gemm(
    const u16* __restrict__ Wb, const bf* __restrict__ act,
    const float* __restrict__ bias, const TRES* __restrict__ resid,
    TOUT* __restrict__ out, int Oc)
{
  __shared__ u16 As[2][4608];     // [128][36]
  __shared__ u16 Bs[2][4096];     // [128][32]
  int t  = threadIdx.x;
  int n0 = blockIdx.x * 128;
  int o0 = blockIdx.y * 128;
  int b  = n0 >> 14;
  int sp = n0 & (HWs-1);
  const u16* actu = (const u16*)act + (size_t)b*256*HWs + sp;

  int kp = t & 15;
  int ns = (t >> 4) << 3;
  int lane = t & 63;
  int wv = t >> 6;
  int wr = (wv >> 1) << 6;
  int wc = (wv & 1) << 6;
  int fr = lane & 15;
  int kg = lane >> 4;
  int arow = t >> 1;
  int ahalf = (t & 1) << 4;

  f32x4 acc[4][4] = {};

  auto loadB = [&](int ks, u32x4& u, u32x4& v){
    const u16* r0 = actu + (size_t)(ks*32 + 2*kp)*HWs + ns;
    u = *(const u32x4*)r0;
    v = *(const u32x4*)(r0 + HWs);
  };
  auto writeB = [&](const u32x4& u, const u32x4& v, int buf){
    u32 w0=(u.x&0xffffu)|(v.x<<16), w1=(u.x>>16)|(v.x&0xffff0000u);
    u32 w2=(u.y&0xffffu)|(v.y<<16), w3=(u.y>>16)|(v.y&0xffff0000u);
    u32 w4=(u.z&0xffffu)|(v.z<<16), w5=(u.z>>16)|(v.z&0xffff0000u);
    u32 w6=(u.w&0xffffu)|(v.w<<16), w7=(u.w>>16)|(v.w&0xffff0000u);
    u16* bp = Bs[buf];
    int c0 = kp*2;
    *(u32*)&bp[(ns+0)*32+c0]=w0; *(u32*)&bp[(ns+1)*32+c0]=w1;
    *(u32*)&bp[(ns+2)*32+c0]=w2; *(u32*)&bp[(ns+3)*32+c0]=w3;
    *(u32*)&bp[(ns+4)*32+c0]=w4; *(u32*)&bp[(ns+5)*32+c0]=w5;
    *(u32*)&bp[(ns+6)*32+c0]=w6; *(u32*)&bp[(ns+7)*32+c0]=w7;
  };
  auto loadA = [&](int ks, u32x4& a0, u32x4& a1){
    const u16* ap = Wb + (size_t)(o0+arow)*256 + ks*32 + ahalf;
    a0 = *(const u32x4*)ap;
    a1 = *(const u32x4*)(ap + 8);
  };
  auto writeA = [&](const u32x4& a0, const u32x4& a1, int buf){
    u16* dst = &As[buf][arow*36 + ahalf];
    *(u32x4*)dst = a0;
    *(u32x4*)(dst+8) = a1;
  };

  {
    u32x4 bu, bvv, a0, a1;
    loadB(0, bu, bvv); loadA(0, a0, a1);
    writeB(bu, bvv, 0); writeA(a0, a1, 0);
  }
  #pragma unroll
  for(int ks=0; ks<8; ++ks){
    int cur = ks & 1;
    __syncthreads();
    u32x4 bu, bvv, a0, a1;
    if (ks < 7){ loadB(ks+1, bu, bvv); loadA(ks+1, a0, a1); }
    bf16x8 af[4], bfr[4];
    #pragma unroll
    for(int j=0;j<4;j++)
      bfr[j] = *(const bf16x8*)&Bs[cur][(wc + j*16 + fr)*32 + kg*8];
    #pragma unroll
    for(int i=0;i<4;i++)
      af[i] = *(const bf16x8*)&As[cur][(wr + i*16 + fr)*36 + kg*8];
    #pragma unroll
    for(int i=0;i<4;i++)
      #pragma unroll
      for(int j=0;j<4;j++)
        acc[i][j] = __builtin_amdgcn_mfma_f32_16x16x32_bf16(af[i], bfr[j], acc[i][j], 0, 0, 0);
    if (ks < 7){ writeB(bu, bvv, cur^1); writeA(a0, a1, cur^1); }
  }

  #pragma unroll
  for(int i=0;i<4;i++){
    #pragma unroll
    for(int reg=0;reg<4;reg++){
      int o = o0 + wr + i*16 + kg*4 + reg;
      size_t rowoff = ((size_t)b*Oc + o)*HWs + sp + wc + fr;
      float bia = bias ? bias[o] : 0.f;
      #pragma unroll
      for(int j=0;j<4;j++){
        float val = acc[i][j][reg] + bia;
        size_t pidx = rowoff + (size_t)(j*16);
        if (resid) val += ldf(resid + pidx);
        sto(out + pidx, val);
      }
    }
  }
}

// [128 rows][128 bf16] LDS plane swizzle: 16B-chunk XOR by row&7 + row-bit3 half-flip
#define SWB(r,c2) ((r)*256 + ((c2) ^ ((((r)&7)<<4)) ^ ((((r)>>3)&1)<<6)))

// ---------------- MFMA axial attention (R11 structure — proven 85us) ----------------
__global__ __launch_bounds__(256, 2) void attn_mfma(const bf* __restrict__ qkv,
    const float* __restrict__ scale, bf* __restrict__ outp,
    const bf* __restrict__ conv, const float* __restrict__ cwaw){
  __shared__ u16 LB0[16384];
  __shared__ u16 LB1[16384];
  __shared__ float2 red2[4];
  int s  = blockIdx.x;
  int b  = s >> 8;
  int ch = s & 255;
  const u16* qp = (const u16*)qkv + ((size_t)b*768 + ch)*HWs;
  const u16* kp = qp + (size_t)256*HWs;
  const u16* vp = qp + (size_t)512*HWs;
  int t = threadIdx.x;

  int lane = t & 63, wvi = t >> 6;
  int fr = lane & 15, kg = lane >> 4;
  int nb = wvi << 5;
  int rr = t >> 1, hb = (t & 1) << 7;
  int kp2 = (t & 15)*2, cs = (t >> 4) << 3;

  auto nat_load = [&](const u16* src, u32x4* R){
    #pragma unroll
    for(int i=0;i<8;i++)
      R[i] = *(const u32x4*)((const char*)src + rr*256 + hb + i*16);
  };
  auto nat_write = [&](const u32x4* R, u16* dst){
    #pragma unroll
    for(int i=0;i<8;i++)
      *(u32x4*)((char*)dst + SWB(rr, hb + i*16)) = R[i];
  };
  auto nat_write_sum = [&](const u32x4* R, u16* dst) -> float {
    float ssum = 0.f;
    #pragma unroll
    for(int i=0;i<8;i++){
      *(u32x4*)((char*)dst + SWB(rr, hb + i*16)) = R[i];
      #pragma unroll
      for(int q=0;q<4;q++){
        float a0, a1;
        unpack2(((const u32*)&R[i])[q], a0, a1);
        ssum += a0*a0 + a1*a1;
      }
    }
    return ssum;
  };
  auto tr_load = [&](const u16* src, u32x4* R){
    #pragma unroll
    for(int bi=0;bi<4;bi++){
      int sr = bi*32 + kp2;
      R[2*bi]   = *(const u32x4*)(src + sr*128 + cs);
      R[2*bi+1] = *(const u32x4*)(src + (sr+1)*128 + cs);
    }
  };
  auto tr_load_lds = [&](const u16* lb, u32x4* R){
    #pragma unroll
    for(int bi=0;bi<4;bi++){
      int sr = bi*32 + kp2;
      R[2*bi]   = *(const u32x4*)((const char*)lb + SWB(sr,   cs*2));
      R[2*bi+1] = *(const u32x4*)((const char*)lb + SWB(sr+1, cs*2));
    }
  };
  auto tr_write = [&](const u32x4* R, u16* dst){
    #pragma unroll
    for(int bi=0;bi<4;bi++){
      int sr = bi*32 + kp2;
      #pragma unroll
      for(int j=0;j<8;j++){
        u32 uw = ((const u32*)&R[2*bi])[j>>1];
        u32 vw = ((const u32*)&R[2*bi+1])[j>>1];
        u32 wv = (j&1) ? ((uw>>16) | (vw & 0xffff0000u))
                       : ((uw & 0xffffu) | (vw<<16));
        *(u32*)((char*)dst + SWB(cs+j, sr*2)) = wv;
      }
    }
  };

  f32x4 acc[8][2];
  f32x4 oacc[8][2];
  const f32x4 vzero = {};
  float ls = 0.f;

  auto mmloop = [&](const u16* afsrc, const u16* bfsrc, f32x4 (&A)[8][2]){
    #pragma unroll
    for(int kk=0;kk<128;kk+=32){
      int kb2 = kk*2 + kg*16;
      bf16x8 b0 = *(const bf16x8*)((const char*)bfsrc + SWB(nb+fr,    kb2));
      bf16x8 b1 = *(const bf16x8*)((const char*)bfsrc + SWB(nb+16+fr, kb2));
      #pragma unroll
      for(int mt=0;mt<8;mt++){
        bf16x8 a0 = *(const bf16x8*)((const char*)afsrc + SWB(mt*16+fr, kb2));
        A[mt][0] = __builtin_amdgcn_mfma_f32_16x16x32_bf16(a0, b0, A[mt][0], 0, 0, 0);
        A[mt][1] = __builtin_amdgcn_mfma_f32_16x16x32_bf16(a0, b1, A[mt][1], 0, 0, 0);
      }
    }
  };

  auto writeCT = [&](u16* dst, f32x4 (&A)[8][2]){
    #pragma unroll
    for(int nt=0;nt<2;nt++){
      int n = nb + nt*16 + fr;
      #pragma unroll
      for(int mt=0;mt<8;mt++){
        #pragma unroll
        for(int pr=0;pr<2;pr++){
          u32 wv = pack2(A[mt][nt][pr*2], A[mt][nt][pr*2+1]);
          int z2 = (mt*16 + kg*4 + pr*2)*2;
          *(u32*)((char*)dst + SWB(n, z2)) = wv;
        }
      }
    }
  };

  auto softmax = [&](){
    #pragma unroll
    for(int nt=0;nt<2;nt++){
      float mx = -1e30f;
      #pragma unroll
      for(int mt=0;mt<8;mt++)
        #pragma unroll
        for(int rg=0;rg<4;rg++){
          acc[mt][nt][rg] *= ls;
          mx = fmaxf(mx, acc[mt][nt][rg]);
        }
      mx = fmaxf(mx, __shfl_xor(mx,16));
      mx = fmaxf(mx, __shfl_xor(mx,32));
      float sm = 0.f;
      #pragma unroll
      for(int mt=0;mt<8;mt++)
        #pragma unroll
        for(int rg=0;rg<4;rg++){
          float e = __expf(acc[mt][nt][rg]-mx);
          acc[mt][nt][rg] = e; sm += e;
        }
      sm += __shfl_xor(sm,16);
      sm += __shfl_xor(sm,32);
      float inv = 1.0f/sm;
      #pragma unroll
      for(int mt=0;mt<8;mt++)
        #pragma unroll
        for(int rg=0;rg<4;rg++)
          acc[mt][nt][rg] *= inv;
    }
  };

  u32x4 RK[8], RQ[8], RV[8];

  // phase 0: K,Q,V global loads in flight; stage K,Q nat (+lscale sums)
  nat_load(kp, RK);
  nat_load(qp, RQ);
  tr_load(vp, RV);                         // V^T; hides under phase 1
  float sk = nat_write_sum(RK, LB0);
  float sq = nat_write_sum(RQ, LB1);
  #pragma unroll
  for(int off=1; off<64; off<<=1){
    sq += __shfl_xor(sq, off);
    sk += __shfl_xor(sk, off);
  }
  if (lane == 0) red2[wvi] = make_float2(sq, sk);
  __syncthreads();
  {
    float tq = 0.f, tk = 0.f;
    #pragma unroll
    for(int wI=0;wI<4;wI++){ tq += red2[wI].x; tk += red2[wI].y; }
    float nq = fmaxf(sqrtf(tq), 1e-12f);
    float nk = fmaxf(sqrtf(tk), 1e-12f);
    ls = scale[ch & 15] / (nq*nk);
  }

  // phase 1: S0^T + softmax; then pull K^T,Q^T register tiles FROM LDS
  #pragma unroll
  for(int mt=0;mt<8;mt++){ acc[mt][0]=vzero; acc[mt][1]=vzero; }
  mmloop(LB0, LB1, acc);
  softmax();
  tr_load_lds(LB0, RK);                    // K nat still in LB0
  tr_load_lds(LB1, RQ);                    // Q nat still in LB1
  __syncthreads();

  // phase 2: P->LB0, V^T->LB1
  writeCT(LB0, acc);
  tr_write(RV, LB1);
  __syncthreads();

  // phase 3: O0 (A=V^T, B=P)
  #pragma unroll
  for(int mt=0;mt<8;mt++){ oacc[mt][0]=vzero; oacc[mt][1]=vzero; }
  mmloop(LB1, LB0, oacc);
  __syncthreads();

  // phase 4: K^T->LB0, Q^T->LB1; V nat global load issued
  tr_write(RK, LB0);
  tr_write(RQ, LB1);
  nat_load(vp, RV);                        // hides under phase 5
  __syncthreads();

  // phase 5: S1^T + softmax
  #pragma unroll
  for(int mt=0;mt<8;mt++){ acc[mt][0]=vzero; acc[mt][1]=vzero; }
  mmloop(LB0, LB1, acc);
  softmax();
  __syncthreads();

  // phase 6: P->LB0, V->LB1; conv loads issued
  writeCT(LB0, acc);
  nat_write(RV, LB1);
  const u16* cp = (const u16*)conv + ((size_t)b*DIMC + ch)*HWs;
  u32x4 RC[8];
  #pragma unroll
  for(int i=0;i<8;i++)
    RC[i] = *(const u32x4*)(cp + rr*128 + (hb>>1) + i*8);  // hides under phase 7
  __syncthreads();

  // phase 7: O1 accumulates (A=P, B=V)
  mmloop(LB0, LB1, oacc);
  __syncthreads();

  // phase 8: O -> LB0 spatial [h][w]
  writeCT(LB0, oacc);
  __syncthreads();

  // phase 9: copy-out with conv mix
  float cw = cwaw[2*b], aw = cwaw[2*b+1];
  bf* op = outp + ((size_t)b*DIMC + ch)*HWs;
  #pragma unroll
  for(int i=0;i<8;i++){
    int c2 = hb + i*16;
    u32x4 ov = *(const u32x4*)((char*)LB0 + SWB(rr, c2));
    u32x4 res;
    #pragma unroll
    for(int q=0;q<4;q++){
      float o0,o1,c0,c1;
      unpack2(((u32*)&ov)[q], o0, o1);
      unpack2(((const u32*)&RC[i])[q], c0, c1);
      ((u32*)&res)[q] = pack2(cw*c0 + aw*o0, cw*c1 + aw*o1);
    }
    *(u32x4*)((u16*)op + rr*128 + (hb>>1) + i*8) = res;
  }
}

// ---------------- launch ----------------
extern "C" void kernel_launch(void* const* d_in, const int* in_sizes, int n_in,
                              void* d_out, int out_size, void* d_ws, size_t ws_size,
                              hipStream_t stream){
  (void)in_sizes; (void)n_in; (void)out_size; (void)ws_size;
  const float* x       = (const float*)d_in[0];
  const float* ln1_w   = (const float*)d_in[1];
  const float* ln1_b   = (const float*)d_in[2];
  const float* conv3_w = (const float*)d_in[3];
  const float* conv3_b = (const float*)d_in[4];
  const float* conv5_w = (const float*)d_in[5];
  const float* conv5_b = (const float*)d_in[6];
  const float* qkv_w   = (const float*)d_in[7];
  const float* scale   = (const float*)d_in[8];
  const float* g1_w    = (const float*)d_in[9];
  const float* g1_b    = (const float*)d_in[10];
  const float* g2_w    = (const float*)d_in[11];
  const float* g2_b    = (const float*)d_in[12];
  const float* proj_w  = (const float*)d_in[13];
  const float* proj_b  = (const float*)d_in[14];
  const float* ln2_w   = (const float*)d_in[15];
  const float* ln2_b   = (const float*)d_in[16];
  const float* pin_w   = (const float*)d_in[17];
  const float* dw_w    = (const float*)d_in[18];
  const float* pout_w  = (const float*)d_in[19];
  float* out = (float*)d_out;
  char* wsb  = (char*)d_ws;

  const size_t MB = 1024*1024;
  bf* y    = (bf*)(wsb +   0*MB);
  bf* conv = (bf*)(wsb +  32*MB);
  bf* qkv  = (bf*)(wsb +  64*MB);
  bf* attnf= (bf*)(wsb +   0*MB);
  bf* xnew = (bf*)(wsb +  64*MB);
  bf* y2   = (bf*)(wsb +  96*MB);
  bf* p    = (bf*)(wsb +   0*MB);
  bf* m    = (bf*)(wsb +  96*MB);
  u16* Wqkv  = (u16*)(wsb + 160*MB);
  u16* Wproj = Wqkv + 196608;
  u16* Wpin  = Wproj + 65536;
  u16* Wpout = Wpin + 131072;
  float* gp     = (float*)(Wpout + 65536);
  float* cwaw   = gp + 1024;

  cvt_all_kernel<<<1792,256,0,stream>>>(qkv_w, proj_w, pin_w, pout_w,
                                        Wqkv, Wproj, Wpin, Wpout,
                                        196608, 65536, 131072, 65536);

  ln_kernel<<<256,256,0,stream>>>(x, ln1_w, ln1_b, y);
  gp_kernel<<<1024,256,0,stream>>>(y, gp);
  gate_kernel<<<1,256,0,stream>>>(gp, g1_w, g1_b, g2_w, g2_b, cwaw);
  dwconv_kernel<<<8192,256,0,stream>>>(y, conv3_w, conv3_b, conv5_w, conv5_b, conv);
  mfma_gemm<float,bf><<<dim3(512,6),256,0,stream>>>(Wqkv, y, nullptr,
                                        (const float*)nullptr, qkv, 768);
  attn_mfma<<<1024,256,0,stream>>>(qkv, scale, attnf, conv, cwaw);
  mfma_gemm<float,bf><<<dim3(512,2),256,0,stream>>>(Wproj, attnf, proj_b, x, xnew, 256);
  ln2px_kernel<<<128,256,0,stream>>>(xnew, ln2_w, ln2_b, y2);
  mfma_gemm<float,bf><<<dim3(512,4),256,0,stream>>>(Wpin, y2, nullptr,
                                        (const float*)nullptr, p, 512);
  dwconv2_glu_kernel<<<4096,256,0,stream>>>(p, dw_w, m);
  mfma_gemm<bf,float><<<dim3(512,2),256,0,stream>>>(Wpout, m, nullptr, xnew, out, 256);
}